// Round 5
// baseline (423.763 us; speedup 1.0000x reference)
//
#include <hip/hip_runtime.h>

#define BB 512
#define TT 256

typedef __attribute__((ext_vector_type(8)))  short bf8;   // 8 bf16 in 4 VGPRs
typedef __attribute__((ext_vector_type(16))) float f16v;  // MFMA 32x32 acc
typedef __attribute__((ext_vector_type(4)))  float f4v;
typedef __attribute__((ext_vector_type(4)))  unsigned uint4v;

#define MFMA(a,b,c) __builtin_amdgcn_mfma_f32_32x32x16_bf16((a),(b),(c),0,0,0)

static __device__ __forceinline__ unsigned short f2bf_rne(float x) {
    unsigned u = __builtin_bit_cast(unsigned, x);
    return (unsigned short)((u + 0x7FFFu + ((u >> 16) & 1u)) >> 16);
}
static __device__ __forceinline__ float bf2f(unsigned short h) {
    unsigned u = ((unsigned)h) << 16;
    return __builtin_bit_cast(float, u);
}
// v_cvt_pk_bf16_f32: D[15:0] = bf16_rne(S0), D[31:16] = bf16_rne(S1).
// Register-only, schedulable (no volatile, no memory). T12-verified on gfx950.
static __device__ __forceinline__ unsigned cvtpk(float a, float b) {
    unsigned r;
    asm("v_cvt_pk_bf16_f32 %0, %1, %2" : "=v"(r) : "v"(a), "v"(b));
    return r;
}
// RNE hi/lo split of an f32 pair into packed bf16 words: 6 VALU ops per pair
// (vs ~10-12 for the scalar shift/and/sub/pack sequence). |x-(hi+lo)| <~ 2^-18|x|.
static __device__ __forceinline__ void packpair(float x0, float x1,
                                                unsigned& hw, unsigned& lw) {
    hw = cvtpk(x0, x1);
    float hf0 = __builtin_bit_cast(float, hw << 16);
    float hf1 = __builtin_bit_cast(float, hw & 0xFFFF0000u);
    lw = cvtpk(x0 - hf0, x1 - hf1);
}
// pi = swap bits 2 and 3 of a 5-bit row index (involution).
// C-layout(D) with reg (j+8kk) as frag elem j of kk == A-frag of D^T*Pi
// (same lane, same h -- zero cross-lane movement). As B-frag:
// MFMA(A, D-as-B) = A * Pi * D.
static __device__ __forceinline__ int pi(int i) {
    return (i & ~12) | ((i & 4) << 1) | ((i & 8) >> 1);
}
static __device__ __forceinline__ float rl(float x, int l) {
    return __builtin_bit_cast(float,
        __builtin_amdgcn_readlane(__builtin_bit_cast(unsigned, x), l));
}
// C-layout f32 (16 regs) -> bf16 hi/lo A/B operands; reg j+8kk -> elem j of kk.
static __device__ __forceinline__ void packfrag(const f16v X,
        bf8& h0, bf8& l0, bf8& h1, bf8& l1) {
    uint4v H0, L0, H1, L1;
    #pragma unroll
    for (int p = 0; p < 4; ++p) {
        unsigned hw, lw;
        packpair(X[2*p],     X[2*p + 1],     hw, lw);  H0[p] = hw;  L0[p] = lw;
        packpair(X[8 + 2*p], X[8 + 2*p + 1], hw, lw);  H1[p] = hw;  L1[p] = lw;
    }
    h0 = __builtin_bit_cast(bf8, H0);
    l0 = __builtin_bit_cast(bf8, L0);
    h1 = __builtin_bit_cast(bf8, H1);
    l1 = __builtin_bit_cast(bf8, L1);
}
// 4-element rank-4 operand (elems 4-7 zero)
static __device__ __forceinline__ void pack4(float x0, float x1, float x2, float x3,
                                             bf8& hv, bf8& lv) {
    unsigned hw0, lw0, hw1, lw1;
    packpair(x0, x1, hw0, lw0);
    packpair(x2, x3, hw1, lw1);
    uint4v Hv = {hw0, hw1, 0u, 0u};
    uint4v Lv = {lw0, lw1, 0u, 0u};
    hv = __builtin_bit_cast(bf8, Hv);
    lv = __builtin_bit_cast(bf8, Lv);
}

// One chain per wave; single-wave block => no __syncthreads anywhere.
// Step:  P_p = (F P F^T + Q) - W Sinv W^T,  W = F P H^T.
// v10 = v9 (Pi-similarity space, zero cross-lane P-path, symmetric Cramer,
// W-from-T) plus:
//   - packfrag via v_cvt_pk_bf16_f32 (halves the dominant VALU issue block)
//   - correction MFMAs at depth 1 (parallel accs, shallow f32 merge) instead
//     of 3 chained after Cramer
//   - raw v_rcp (skip Newton refine) + balanced det/nG trees in Cramer
__global__ __launch_bounds__(64, 1)
void kalman_v10(const float* __restrict__ obs,
                const float* __restrict__ Fg,
                const float* __restrict__ Qg,
                const float* __restrict__ Hg,
                const float* __restrict__ Rg,
                const float* __restrict__ im,
                const float* __restrict__ ic,
                float* __restrict__ out)
{
    __shared__ __align__(16) float sm[32];

    const int lane = threadIdx.x;
    const int b    = blockIdx.x;
    const int c    = lane & 31;
    const int h    = lane >> 5;

    // PiF (rows pi-permuted, cols plain) -- dual-use as A-frag and B-frag.
    // H plain (rows c<4).
    bf8 Fh[2], Fl[2], Hh[2], Hl[2];
    #pragma unroll
    for (int kk = 0; kk < 2; ++kk) {
        #pragma unroll
        for (int j = 0; j < 8; ++j) {
            int k = kk*16 + h*8 + j;
            float f = Fg[pi(c)*32 + k];
            unsigned short fh = f2bf_rne(f);
            Fh[kk][j] = (short)fh;
            Fl[kk][j] = (short)f2bf_rne(f - bf2f(fh));
            float hv = (c < 4) ? Hg[c*32 + k] : 0.f;
            unsigned short hh = f2bf_rne(hv);
            Hh[kk][j] = (short)hh;
            Hl[kk][j] = (short)f2bf_rne(hv - bf2f(hh));
        }
    }

    // state P := hat(init_cov), Qc := hat(Q) in C-layout; Rcl := R in C-layout
    // (nonzero only rows<4 x cols<4, i.e. h==0, reg<4, c<4).
    f16v Qc, P, Rcl;
    #pragma unroll
    for (int reg = 0; reg < 16; ++reg) {
        int row = (reg & 3) + 8*(reg >> 2) + 4*h;
        Qc[reg]  = Qg[pi(row)*32 + pi(c)];
        P[reg]   = ic[(size_t)b*1024 + pi(row)*32 + pi(c)];
        Rcl[reg] = (reg < 4 && h == 0 && c < 4) ? Rg[reg*4 + c] : 0.f;
    }

    // dot rows hoisted to registers:
    // lanes<32: row pi(lane) of F; lanes>=32: row (lane&3) of H.
    f4v frow[8];
    {
        const float* rowp = (lane < 32) ? (Fg + (size_t)pi(lane)*32)
                                        : (Hg + (size_t)(lane & 3)*32);
        #pragma unroll
        for (int q = 0; q < 8; ++q) frow[q] = *(const f4v*)(rowp + 4*q);
    }
    // sm holds the mean UNPERMUTED; lane c's update lands at sm[pi(c)].
    if (lane < 32) sm[lane] = im[b*32 + lane];

    const bool yl = (lane >= 32 && lane < 36);
    const float* obsp = obs + (size_t)b*TT*4 + (yl ? (lane - 32) : 0);
    float* om = out;
    float* oc = out + (size_t)TT * BB * 4;

    // software-pipelined observation load (consumed one step later)
    float yv = yl ? obsp[0] : 0.f;

    for (int t = 0; t < TT; ++t) {
        // issue next step's obs load NOW; consumed ~full step later
        float yv_nxt = (yl && t + 1 < TT) ? obsp[(t + 1) * 4] : 0.f;

        // lanes<32: (F m)[pi(lane)];  lanes>=32: (H m)[lane&3]
        float dotv = 0.f;
        #pragma unroll
        for (int q = 0; q < 8; ++q) {
            f4v mv = *(const f4v*)&sm[4*q];
            dotv += frow[q].x*mv.x + frow[q].y*mv.y
                  + frow[q].z*mv.z + frow[q].w*mv.w;
        }

        // state operands straight from C-layout regs (no exchange)
        bf8 Dh0, Dl0, Dh1, Dl1;
        packfrag(P, Dh0, Dl0, Dh1, Dl1);

        // U1 = Pi*P*H^T  (cols c>=4 exact zeros) -- same-acc chains are
        // ~full-rate on gfx950 (m233), keep single acc
        f16v uacc = 0.0f;
        uacc = MFMA(Dh0, Hh[0], uacc);  uacc = MFMA(Dh1, Hh[1], uacc);
        uacc = MFMA(Dh0, Hl[0], uacc);  uacc = MFMA(Dh1, Hl[1], uacc);
        uacc = MFMA(Dl0, Hh[0], uacc);  uacc = MFMA(Dl1, Hh[1], uacc);

        // T = Pi*P*F^T*Pi
        f16v tacc = 0.0f;
        tacc = MFMA(Dh0, Fh[0], tacc);  tacc = MFMA(Dh1, Fh[1], tacc);
        tacc = MFMA(Dh0, Fl[0], tacc);  tacc = MFMA(Dh1, Fl[1], tacc);
        tacc = MFMA(Dl0, Fh[0], tacc);  tacc = MFMA(Dl1, Fh[1], tacc);

        // U1 operands from registers
        bf8 Uh0, Ul0, Uh1, Ul1;
        packfrag(uacc, Uh0, Ul0, Uh1, Ul1);

        // S = H*Pi*U1 + R = H*P*H^T + R  (acc starts at C-layout R)
        f16v sacc = Rcl;
        sacc = MFMA(Hh[0], Uh0, sacc);  sacc = MFMA(Hh[1], Uh1, sacc);
        sacc = MFMA(Hh[0], Ul0, sacc);  sacc = MFMA(Hh[1], Ul1, sacc);
        sacc = MFMA(Hl[0], Uh0, sacc);  sacc = MFMA(Hl[1], Uh1, sacc);

        // T operands from registers
        bf8 Th0, Tl0, Th1, Tl1;
        packfrag(tacc, Th0, Tl0, Th1, Tl1);

        // Wt = H*Pi*T = W^T*Pi: lane c regs 0-3 = W[pi(c)][m]
        f16v wacc = 0.0f;
        wacc = MFMA(Hh[0], Th0, wacc);  wacc = MFMA(Hh[1], Th1, wacc);
        wacc = MFMA(Hh[0], Tl0, wacc);  wacc = MFMA(Hh[1], Tl1, wacc);
        wacc = MFMA(Hl[0], Th0, wacc);  wacc = MFMA(Hl[1], Th1, wacc);

        // Z = PiF*Pi*T + hatQ = hat(F*P*F^T + Q)
        f16v zacc = Qc;
        zacc = MFMA(Fh[0], Th0, zacc);  zacc = MFMA(Fh[1], Th1, zacc);
        zacc = MFMA(Fh[0], Tl0, zacc);  zacc = MFMA(Fh[1], Tl1, zacc);
        zacc = MFMA(Fl[0], Th0, zacc);  zacc = MFMA(Fl[1], Th1, zacc);

        // outputs
        if (lane < 32 && c < 4) {
            #pragma unroll
            for (int m = 0; m < 4; ++m)
                oc[(((size_t)t*BB + b)*4 + m)*4 + c] = sacc[m];
        }
        float residv = yv - dotv;                 // valid on lanes 32..35
        if (yl) om[((size_t)t*BB + b)*4 + (lane - 32)] = dotv;

        if (t == TT - 1) break;
        yv = yv_nxt;

        // S lower triangle via v_readlane (S symmetric): sacc[m] on lane n = S[m][n]
        const float sa = rl(sacc[0], 0);
        const float sb = rl(sacc[1], 0), se = rl(sacc[1], 1);
        const float sc = rl(sacc[2], 0), sf = rl(sacc[2], 1), sh = rl(sacc[2], 2);
        const float sd = rl(sacc[3], 0), sg = rl(sacc[3], 1), si = rl(sacc[3], 2),
                    sj = rl(sacc[3], 3);

        const float rv0 = rl(residv, 32), rv1 = rl(residv, 33),
                    rv2 = rl(residv, 34), rv3 = rl(residv, 35);

        float nG0, nG1, nG2, nG3, W0, W1, W2, W3;
        {
            // symmetric 4x4 inverse: 14 unique 2x2 minors, 10 cofactors
            const float m1  = sh*sj - si*si;
            const float m2  = sf*sj - sg*si;
            const float m3  = sf*si - sg*sh;
            const float m4  = sc*sj - sd*si;
            const float m5  = sc*si - sd*sh;
            const float m6  = sc*sg - sd*sf;
            const float m7  = se*sj - sg*sg;
            const float m8  = sb*sj - sd*sg;
            const float m9  = sb*sg - se*sd;
            const float m10 = se*si - sf*sg;
            const float m11 = sb*si - sd*sf;
            const float m12 = se*sh - sf*sf;
            const float m13 = sb*sh - sc*sf;
            const float m14 = sb*sf - sc*se;

            // balanced 2-level trees (no reassociation without fast-math)
            const float C00 =  (se*m1 - sf*m2) + sg*m3;
            const float C01 = -((sb*m1 - sf*m4) + sg*m5);
            const float C02 =  (sb*m2 - se*m4) + sg*m6;
            const float C03 = -((sb*m3 - se*m5) + sf*m6);
            const float C11 =  (sa*m1 - sc*m4) + sd*m5;
            const float C12 = -((sa*m2 - sb*m4) + sd*m6);
            const float C13 =  (sa*m3 - sb*m5) + sc*m6;
            const float C22 =  (sa*m7 - sb*m8) + sd*m9;
            const float C23 = -((sa*m10 - sb*m11) + sc*m9);
            const float C33 =  (sa*m12 - sb*m13) + sc*m14;

            const float det = (sa*C00 + sb*C01) + (sc*C02 + sd*C03);
            // raw v_rcp (~1e-7 rel) is plenty: nG goes to bf16 next anyway
            const float nid = -__builtin_amdgcn_rcpf(det);   // nG = -W*Sinv

            W0 = wacc[0];
            W1 = wacc[1];
            W2 = wacc[2];
            W3 = wacc[3];

            nG0 = nid * ((W0*C00 + W1*C01) + (W2*C02 + W3*C03));
            nG1 = nid * ((W0*C01 + W1*C11) + (W2*C12 + W3*C13));
            nG2 = nid * ((W0*C02 + W1*C12) + (W2*C22 + W3*C23));
            nG3 = nid * ((W0*C03 + W1*C13) + (W2*C23 + W3*C33));
        }

        // rank-4 correction in hat space: corr = (Pi nG)(Pi W)^T.
        // Depth-1 after Cramer: one term chains into zacc, two into fresh
        // accs (zero-inits hoistable into the Cramer window), shallow merge.
        bf8 Gh, Gl, Wbh, Wbl;
        pack4(nG0, nG1, nG2, nG3, Gh, Gl);
        pack4(W0,  W1,  W2,  W3,  Wbh, Wbl);
        f16v c2 = 0.0f, c3 = 0.0f;
        zacc = MFMA(Gh, Wbh, zacc);
        c2   = MFMA(Gh, Wbl, c2);
        c3   = MFMA(Gl, Wbh, c3);
        P = zacc + (c2 + c3);

        // mean: lane c computes m'[pi(c)] = (Fm)[pi(c)] - nG[pi(c)].resid
        // and stores at sm[pi(c)] so sm stays unpermuted.
        if (lane < 32)
            sm[pi(lane)] = dotv - (nG0*rv0 + nG1*rv1 + nG2*rv2 + nG3*rv3);
    }
}

extern "C" void kernel_launch(void* const* d_in, const int* in_sizes, int n_in,
                              void* d_out, int out_size, void* d_ws, size_t ws_size,
                              hipStream_t stream) {
    const float* obs       = (const float*)d_in[0];
    const float* F         = (const float*)d_in[1];
    const float* Q         = (const float*)d_in[2];
    const float* H         = (const float*)d_in[3];
    const float* R         = (const float*)d_in[4];
    const float* init_mean = (const float*)d_in[5];
    const float* init_cov  = (const float*)d_in[6];
    float* out = (float*)d_out;

    kalman_v10<<<BB, 64, 0, stream>>>(obs, F, Q, H, R, init_mean, init_cov, out);
}